// Round 9
// baseline (200.326 us; speedup 1.0000x reference)
//
#include <hip/hip_runtime.h>
#include <hip/hip_bf16.h>
#include <math.h>

// Problem constants
#define Bn   2
#define Nn   2048
#define Kn   48
#define Cn   128
#define G2   16     // nodes per block in the tail kernel

typedef short bf16x8 __attribute__((ext_vector_type(8)));
typedef float f32x4  __attribute__((ext_vector_type(4)));

#if __has_builtin(__builtin_amdgcn_cvt_pk_bf16_f32)
#define HAS_PK 1
#endif

__device__ __forceinline__ short f2bf(float f) {
  union { float f; unsigned u; } v; v.f = f;
  unsigned r = v.u + 0x7fffu + ((v.u >> 16) & 1u);
  return (short)(r >> 16);
}

__device__ __forceinline__ unsigned pk2(float a, float b) {
#ifdef HAS_PK
  auto p = __builtin_amdgcn_cvt_pk_bf16_f32(a, b);
  return __builtin_bit_cast(unsigned, p);
#else
  return (unsigned)(unsigned short)f2bf(a) | ((unsigned)(unsigned short)f2bf(b) << 16);
#endif
}

// tanh-GELU with exp2-folded constants; |err| vs erf-gelu ~3e-4.
__device__ __forceinline__ float gelu_f(float x) {
  float z = x * (-2.3021991f - 0.10294200f * x * x);
  float e = __builtin_amdgcn_exp2f(z);
  return x * __builtin_amdgcn_rcpf(1.0f + e);
}

// LDS-visibility barrier without __syncthreads' vmcnt(0) drain.
#define LBAR()                                              \
  do {                                                      \
    __builtin_amdgcn_sched_barrier(0);                      \
    asm volatile("s_waitcnt lgkmcnt(0)" ::: "memory");      \
    __builtin_amdgcn_s_barrier();                           \
    __builtin_amdgcn_sched_barrier(0);                      \
  } while (0)

// ---------------------------------------------------------------------------
// Pack weights into bf16 MFMA B-fragment tiles (512 shorts each; lane l holds
// 8 bf16 = W[kt*32 + (l>>4)*8 + j][nt*16 + (l&15)]).
// ws (shorts): W1i [0,16384) | W1e [16384,49152) | W2 [49152,65536)
//              W3 [65536,81920) | Wu [81920,98304)
// ---------------------------------------------------------------------------
__global__ void pack_weights(const float* __restrict__ W1,
                             const float* __restrict__ W2,
                             const float* __restrict__ W3,
                             const float* __restrict__ Wu,
                             short* __restrict__ ws) {
  int tid = blockIdx.x * blockDim.x + threadIdx.x;
  if (tid >= 192 * 64) return;
  int lane = tid & 63;
  int tile = tid >> 6;
  const float* W; short* dst;
  if (tile < 32)       { W = W1;         dst = ws; }
  else if (tile < 96)  { W = W1 + 16384; dst = ws + 16384; tile -= 32; }
  else if (tile < 128) { W = W2;         dst = ws + 49152; tile -= 96; }
  else if (tile < 160) { W = W3;         dst = ws + 65536; tile -= 128; }
  else                 { W = Wu;         dst = ws + 81920; tile -= 160; }
  int kt = tile >> 3, nt = tile & 7;
  int n  = nt * 16 + (lane & 15);
  int k0 = kt * 32 + (lane >> 4) * 8;
  union { short s[8]; bf16x8 v; } u8;
#pragma unroll
  for (int j = 0; j < 8; j++) u8.s[j] = f2bf(W[(k0 + j) * 128 + n]);
  *reinterpret_cast<bf16x8*>(dst + (tile << 9) + lane * 8) = u8.v;
}

// ---------------------------------------------------------------------------
// Kernel 1 (Round 9): TWO nodes per block, 512 thr = 8 waves, 2M x 4N wave
// decomposition. Wave (wm=wave>>2, wn=wave&3) owns rows [wm*48,wm*48+48)
// (= node wm's 48 edges exactly) x cols [wn*32,wn*32+32).
// WHY: pipe-level accounting across r2-r8 shows the CU-shared LDS pipe is
// the saturated resource (~70-80% of runtime), because every wave was
// reading the FULL 96-row A-tile in all 3 GEMM phases (576 ds_read_b128 per
// pair). The 2M split halves A-reads (24->12 per wave-phase, 576->288/pair);
// MFMA count per wave unchanged (3m x 2n x 4kt). B fragments double per wave
// (2 tiles per kt, L2-hot). accY and the GEMM2 column-sum become per-node-
// private per wave (M-split coincides with the node A/B row boundary).
// Skeleton (LBAR no-vmcnt barriers, issue-early gather/edge) kept from r8.
// ---------------------------------------------------------------------------
__global__ __launch_bounds__(512, 4)
void node_update_kernel(const float* __restrict__ node_h,
                        const float* __restrict__ edge_h,
                        const int*   __restrict__ edge_index,
                        const short* __restrict__ wpack,
                        const float* __restrict__ b1,
                        const float* __restrict__ b2,
                        float* __restrict__ hs_out) {
  // LDS (bytes), 49664 total:
  //  [0,24576)      Xs 96x128 bf16 swz (node_j); H1s overlays after GEMM1a
  //  [24576,49152)  Es 96x128 bf16 swz (edge)
  //  [49152,49664)  nhb: node_i bf16 x256 (2 nodes)
  __shared__ __align__(16) char smem[49664];
  short* Xs  = (short*)smem;
  short* H1s = (short*)smem;             // overlay of Xs
  short* Es  = (short*)(smem + 24576);
  short* nhb = (short*)(smem + 49152);

  const int tid  = threadIdx.x;
  const int n0   = blockIdx.x * 2;     // first node of the pair
  const int bb   = n0 >> 11;           // batch (pair never straddles: 2048 even)
  const int lane = tid & 63;
  const int wave = tid >> 6;           // 0..7
  const int wn   = wave & 3;           // N-tile: cols [wn*32, wn*32+32)
  const int wm   = wave >> 2;          // M-half: rows [wm*48,..) = node wm
  const int lr   = lane & 15;
  const int lq   = lane >> 4;
  const int gw   = tid & 15;           // 16B granule within row
  const int gr   = tid >> 4;           // 0..31

  const short* W1i = wpack;
  const short* W1e = wpack + 16384;
  const short* W2p = wpack + 49152;

  // ---- P0: hoist W1i frags (2 col-tiles) + biases, idx->regs, stage nhb ----
  bf16x8 w1i0[4], w1i1[4];
#pragma unroll
  for (int kt = 0; kt < 4; kt++) {
    w1i0[kt] = *reinterpret_cast<const bf16x8*>(W1i + ((kt * 8 + 2 * wn)     << 9) + lane * 8);
    w1i1[kt] = *reinterpret_cast<const bf16x8*>(W1i + ((kt * 8 + 2 * wn + 1) << 9) + lane * 8);
  }
  const int col0 = wn * 32 + lr;
  const int col1 = col0 + 16;
  const float b1v0 = b1[col0], b1v1 = b1[col1];
  const float b2v0 = b2[col0], b2v1 = b2[col1];
  int idxr[3];
#pragma unroll
  for (int k = 0; k < 3; k++)
    idxr[k] = edge_index[n0 * Kn + gr + k * 32];
  if (tid < 256) nhb[tid] = f2bf(node_h[(size_t)n0 * Cn + tid]);
  LBAR();   // B1: nhb visible

  // ---- P2: issue gather (idx regs have landed) ----
  float4 na[3], nb[3];
#pragma unroll
  for (int k = 0; k < 3; k++) {
    const float* src = node_h + ((size_t)(bb * Nn) + idxr[k]) * Cn + gw * 8;
    na[k] = *reinterpret_cast<const float4*>(src);
    nb[k] = *reinterpret_cast<const float4*>(src + 4);
  }
  __builtin_amdgcn_sched_barrier(0);   // pin: gather issued HERE

  // ---- P3: issue edge (consumed after GEMM1a) ----
  float4 ea[3], eb[3];
#pragma unroll
  for (int k = 0; k < 3; k++) {
    int r = gr + k * 32;
    const float* src = edge_h + ((size_t)n0 * Kn + r) * Cn + gw * 8;
    ea[k] = *reinterpret_cast<const float4*>(src);
    eb[k] = *reinterpret_cast<const float4*>(src + 4);
  }
  __builtin_amdgcn_sched_barrier(0);   // pin: edge issued HERE

  // ---- P4: accY row-vector MFMAs for THIS wave's node (wm), 2 col-frags ----
  f32x4 accY0 = {}, accY1 = {};
#pragma unroll
  for (int kt = 0; kt < 4; kt++) {
    bf16x8 av = {};
    if (lr == 0)
      av = *reinterpret_cast<const bf16x8*>(&nhb[wm * 128 + kt * 32 + lq * 8]);
    accY0 = __builtin_amdgcn_mfma_f32_16x16x32_bf16(av, w1i0[kt], accY0, 0, 0, 0);
    accY1 = __builtin_amdgcn_mfma_f32_16x16x32_bf16(av, w1i1[kt], accY1, 0, 0, 0);
  }
  const float yi0 = __shfl(accY0[0], lr) + b1v0;
  const float yi1 = __shfl(accY1[0], lr) + b1v1;

  // ---- P5: convert gather -> Xs (edge loads stay in flight) ----
#pragma unroll
  for (int k = 0; k < 3; k++) {
    int r = gr + k * 32;
    uint4 p;
    p.x = pk2(na[k].x, na[k].y); p.y = pk2(na[k].z, na[k].w);
    p.z = pk2(nb[k].x, nb[k].y); p.w = pk2(nb[k].z, nb[k].w);
    *reinterpret_cast<uint4*>(&Xs[r * 128 + ((gw ^ (r & 7)) << 3)]) = p;
  }
  LBAR();   // B2: Xs visible; edge loads cross un-drained

  // ---- P6: GEMM1a (rows wm*48.., cols wn*32..; 12 A-reads, 24 MFMA) ----
  f32x4 acc[3][2] = {};
#pragma unroll
  for (int kt = 0; kt < 4; kt++) {
    bf16x8 bf0 = *reinterpret_cast<const bf16x8*>(W1e + ((kt * 8 + 2 * wn)     << 9) + lane * 8);
    bf16x8 bf1 = *reinterpret_cast<const bf16x8*>(W1e + ((kt * 8 + 2 * wn + 1) << 9) + lane * 8);
    int sw = (((kt * 4 + lq) ^ (lr & 7)) << 3);
#pragma unroll
    for (int mt = 0; mt < 3; mt++) {
      bf16x8 a = *reinterpret_cast<const bf16x8*>(&Xs[(wm * 48 + mt * 16 + lr) * 128 + sw]);
      acc[mt][0] = __builtin_amdgcn_mfma_f32_16x16x32_bf16(a, bf0, acc[mt][0], 0, 0, 0);
      acc[mt][1] = __builtin_amdgcn_mfma_f32_16x16x32_bf16(a, bf1, acc[mt][1], 0, 0, 0);
    }
  }

  // ---- P7: convert edge -> Es (separate buffer) ----
#pragma unroll
  for (int k = 0; k < 3; k++) {
    int r = gr + k * 32;
    uint4 p;
    p.x = pk2(ea[k].x, ea[k].y); p.y = pk2(ea[k].z, ea[k].w);
    p.z = pk2(eb[k].x, eb[k].y); p.w = pk2(eb[k].z, eb[k].w);
    *reinterpret_cast<uint4*>(&Es[r * 128 + ((gw ^ (r & 7)) << 3)]) = p;
  }
  LBAR();   // B3: Es visible; all Xs reads (P6) done

  // ---- P8: GEMM1b (edge half @ W1[256:384]) ----
#pragma unroll
  for (int kt = 0; kt < 4; kt++) {
    bf16x8 bf0 = *reinterpret_cast<const bf16x8*>(W1e + (((kt + 4) * 8 + 2 * wn)     << 9) + lane * 8);
    bf16x8 bf1 = *reinterpret_cast<const bf16x8*>(W1e + (((kt + 4) * 8 + 2 * wn + 1) << 9) + lane * 8);
    int sw = (((kt * 4 + lq) ^ (lr & 7)) << 3);
#pragma unroll
    for (int mt = 0; mt < 3; mt++) {
      bf16x8 a = *reinterpret_cast<const bf16x8*>(&Es[(wm * 48 + mt * 16 + lr) * 128 + sw]);
      acc[mt][0] = __builtin_amdgcn_mfma_f32_16x16x32_bf16(a, bf0, acc[mt][0], 0, 0, 0);
      acc[mt][1] = __builtin_amdgcn_mfma_f32_16x16x32_bf16(a, bf1, acc[mt][1], 0, 0, 0);
    }
  }

  // ---- P9: epilogue +yi +b1, gelu, bf16 -> H1s (overlay Xs; safe post-B3) ----
  {
    const int g0 = col0 >> 3, cl0 = col0 & 7;
    const int g1 = col1 >> 3, cl1 = col1 & 7;
#pragma unroll
    for (int mt = 0; mt < 3; mt++) {
      int r0 = wm * 48 + mt * 16 + lq * 4;
      {
        float v0 = gelu_f(acc[mt][0][0] + yi0);
        float v1 = gelu_f(acc[mt][0][1] + yi0);
        float v2 = gelu_f(acc[mt][0][2] + yi0);
        float v3 = gelu_f(acc[mt][0][3] + yi0);
        unsigned p01 = pk2(v0, v1), p23 = pk2(v2, v3);
        H1s[(r0 + 0) * 128 + ((g0 ^ ((r0 + 0) & 7)) << 3) + cl0] = (short)(p01 & 0xffff);
        H1s[(r0 + 1) * 128 + ((g0 ^ ((r0 + 1) & 7)) << 3) + cl0] = (short)(p01 >> 16);
        H1s[(r0 + 2) * 128 + ((g0 ^ ((r0 + 2) & 7)) << 3) + cl0] = (short)(p23 & 0xffff);
        H1s[(r0 + 3) * 128 + ((g0 ^ ((r0 + 3) & 7)) << 3) + cl0] = (short)(p23 >> 16);
      }
      {
        float v0 = gelu_f(acc[mt][1][0] + yi1);
        float v1 = gelu_f(acc[mt][1][1] + yi1);
        float v2 = gelu_f(acc[mt][1][2] + yi1);
        float v3 = gelu_f(acc[mt][1][3] + yi1);
        unsigned p01 = pk2(v0, v1), p23 = pk2(v2, v3);
        H1s[(r0 + 0) * 128 + ((g1 ^ ((r0 + 0) & 7)) << 3) + cl1] = (short)(p01 & 0xffff);
        H1s[(r0 + 1) * 128 + ((g1 ^ ((r0 + 1) & 7)) << 3) + cl1] = (short)(p01 >> 16);
        H1s[(r0 + 2) * 128 + ((g1 ^ ((r0 + 2) & 7)) << 3) + cl1] = (short)(p23 & 0xffff);
        H1s[(r0 + 3) * 128 + ((g1 ^ ((r0 + 3) & 7)) << 3) + cl1] = (short)(p23 >> 16);
      }
    }
  }
  LBAR();   // B4: H1s visible

  // ---- P10: GEMM2 (rows wm*48.. of H1s @ W2 cols wn*32..), gelu+colsum ----
  f32x4 acc2[3][2] = {};
#pragma unroll
  for (int kt = 0; kt < 4; kt++) {
    bf16x8 bf0 = *reinterpret_cast<const bf16x8*>(W2p + ((kt * 8 + 2 * wn)     << 9) + lane * 8);
    bf16x8 bf1 = *reinterpret_cast<const bf16x8*>(W2p + ((kt * 8 + 2 * wn + 1) << 9) + lane * 8);
    int sw = (((kt * 4 + lq) ^ (lr & 7)) << 3);
#pragma unroll
    for (int mt = 0; mt < 3; mt++) {
      bf16x8 a = *reinterpret_cast<const bf16x8*>(&H1s[(wm * 48 + mt * 16 + lr) * 128 + sw]);
      acc2[mt][0] = __builtin_amdgcn_mfma_f32_16x16x32_bf16(a, bf0, acc2[mt][0], 0, 0, 0);
      acc2[mt][1] = __builtin_amdgcn_mfma_f32_16x16x32_bf16(a, bf1, acc2[mt][1], 0, 0, 0);
    }
  }
  {
    float s0 = 0.f, s1 = 0.f;
#pragma unroll
    for (int mt = 0; mt < 3; mt++)
#pragma unroll
      for (int r = 0; r < 4; r++) {
        s0 += gelu_f(acc2[mt][0][r] + b2v0);
        s1 += gelu_f(acc2[mt][1][r] + b2v1);
      }
    s0 += __shfl_xor(s0, 16);
    s0 += __shfl_xor(s0, 32);
    s1 += __shfl_xor(s1, 16);
    s1 += __shfl_xor(s1, 32);
    if (lq == 0) {
      // rows [wm*48, wm*48+48) are exactly node wm's 48 edges
      hs_out[(size_t)(n0 + wm) * Cn + col0] = s0;
      hs_out[(size_t)(n0 + wm) * Cn + col1] = s1;
    }
  }
}

// ---------------------------------------------------------------------------
// Kernel 2 (tail, batched): 16 nodes per block.
// msg = (hs @ W3 + 48*b3)/30 ; x = nh + msg ; u = LN(x) ;
// y = nh + u@Wu + bu ; out = LN(y).  Matvecs are dense M=16 MFMA GEMMs.
// Reads hs from the out buffer, overwrites the same rows at the end.
// ---------------------------------------------------------------------------
__global__ __launch_bounds__(256, 4)
void tail_kernel(const float* __restrict__ node_h,
                 const short* __restrict__ wpack,
                 const float* __restrict__ b3,
                 const float* __restrict__ bu,
                 const float* __restrict__ ln_g,
                 const float* __restrict__ ln_b,
                 float* __restrict__ out) {
  // LDS: hsB 16x128 bf16 swz [0,4096) | nhr 16x128 f32 [4096,12288)
  //      xs 16x132 f32 [12288,20736) | usB 16x128 bf16 swz [20736,24832)
  __shared__ __align__(16) char sm2[24832];
  short* hsB = (short*)sm2;
  float* nhr = (float*)(sm2 + 4096);
  float* xs  = (float*)(sm2 + 12288);
  short* usB = (short*)(sm2 + 20736);

  const int tid  = threadIdx.x;
  const int lane = tid & 63;
  const int wave = tid >> 6;
  const int lr   = lane & 15;
  const int lq   = lane >> 4;
  const int n0   = blockIdx.x * G2;

  const short* W3p = wpack + 65536;
  const short* Wup = wpack + 81920;

  // ---- stage node_h (f32) and hs (bf16, swizzled) ----
  {
    int row = tid >> 4, seg = tid & 15;
    const float* p = node_h + (size_t)(n0 + row) * Cn + seg * 8;
    float4 a0 = *reinterpret_cast<const float4*>(p);
    float4 a1 = *reinterpret_cast<const float4*>(p + 4);
    *reinterpret_cast<float4*>(&nhr[row * 128 + seg * 8])     = a0;
    *reinterpret_cast<float4*>(&nhr[row * 128 + seg * 8 + 4]) = a1;
    const float* q = out + (size_t)(n0 + row) * Cn + seg * 8;  // hs scratch
    float4 c0 = *reinterpret_cast<const float4*>(q);
    float4 c1 = *reinterpret_cast<const float4*>(q + 4);
    uint4 pk;
    pk.x = pk2(c0.x, c0.y); pk.y = pk2(c0.z, c0.w);
    pk.z = pk2(c1.x, c1.y); pk.w = pk2(c1.z, c1.w);
    *reinterpret_cast<uint4*>(&hsB[row * 128 + ((seg ^ (row & 7)) << 3)]) = pk;
  }
  __syncthreads();

  // ---- msg GEMM (M=16): hs @ W3 ; x = nh + (.+48*b3)/30 -> xs ----
  f32x4 am[2] = {};
#pragma unroll
  for (int kt = 0; kt < 4; kt++) {
    bf16x8 av = *reinterpret_cast<const bf16x8*>(&hsB[lr * 128 + (((kt * 4 + lq) ^ (lr & 7)) << 3)]);
    bf16x8 bv0 = *reinterpret_cast<const bf16x8*>(W3p + ((kt * 8 + wave * 2 + 0) << 9) + lane * 8);
    bf16x8 bv1 = *reinterpret_cast<const bf16x8*>(W3p + ((kt * 8 + wave * 2 + 1) << 9) + lane * 8);
    am[0] = __builtin_amdgcn_mfma_f32_16x16x32_bf16(av, bv0, am[0], 0, 0, 0);
    am[1] = __builtin_amdgcn_mfma_f32_16x16x32_bf16(av, bv1, am[1], 0, 0, 0);
  }
#pragma unroll
  for (int j = 0; j < 2; j++) {
    int col = (wave * 2 + j) * 16 + lr;
    float bb = 48.0f * b3[col];
#pragma unroll
    for (int r = 0; r < 4; r++) {
      int row = lq * 4 + r;
      xs[row * 132 + col] = nhr[row * 128 + col] + (am[j][r] + bb) * (1.0f / 30.0f);
    }
  }
  __syncthreads();

  // ---- LN1 -> usB (bf16 swz). Wave handles 4 rows; lane owns cols lane,lane+64.
  const float lg1 = ln_g[lane],      lb1v = ln_b[lane];
  const float lg2 = ln_g[lane + 64], lb2v = ln_b[lane + 64];
#pragma unroll
  for (int s = 0; s < 4; s++) {
    int row = wave * 4 + s;
    float v1 = xs[row * 132 + lane];
    float v2 = xs[row * 132 + lane + 64];
    float s1 = v1 + v2, s2 = v1 * v1 + v2 * v2;
#pragma unroll
    for (int off = 32; off >= 1; off >>= 1) {
      s1 += __shfl_xor(s1, off);
      s2 += __shfl_xor(s2, off);
    }
    float mu = s1 * (1.f / 128.f);
    float var = s2 * (1.f / 128.f) - mu * mu;
    float rstd = rsqrtf(var + 1e-5f);
    unsigned u12 = pk2((v1 - mu) * rstd * lg1 + lb1v,
                       (v2 - mu) * rstd * lg2 + lb2v);
    int sw = (row & 7);
    usB[row * 128 + (((lane >> 3) ^ sw) << 3) + (lane & 7)]       = (short)(u12 & 0xffff);
    usB[row * 128 + ((((lane >> 3) + 8) ^ sw) << 3) + (lane & 7)] = (short)(u12 >> 16);
  }
  __syncthreads();

  // ---- upd GEMM (M=16): u @ Wu ; y = nh + . + bu -> xs ----
  f32x4 au[2] = {};
#pragma unroll
  for (int kt = 0; kt < 4; kt++) {
    bf16x8 av = *reinterpret_cast<const bf16x8*>(&usB[lr * 128 + (((kt * 4 + lq) ^ (lr & 7)) << 3)]);
    bf16x8 bv0 = *reinterpret_cast<const bf16x8*>(Wup + ((kt * 8 + wave * 2 + 0) << 9) + lane * 8);
    bf16x8 bv1 = *reinterpret_cast<const bf16x8*>(Wup + ((kt * 8 + wave * 2 + 1) << 9) + lane * 8);
    au[0] = __builtin_amdgcn_mfma_f32_16x16x32_bf16(av, bv0, au[0], 0, 0, 0);
    au[1] = __builtin_amdgcn_mfma_f32_16x16x32_bf16(av, bv1, au[1], 0, 0, 0);
  }
  __syncthreads();   // xs LN1 reads done before overwrite
#pragma unroll
  for (int j = 0; j < 2; j++) {
    int col = (wave * 2 + j) * 16 + lr;
    float bb = bu[col];
#pragma unroll
    for (int r = 0; r < 4; r++) {
      int row = lq * 4 + r;
      xs[row * 132 + col] = nhr[row * 128 + col] + au[j][r] + bb;
    }
  }
  __syncthreads();

  // ---- LN2 -> out ----
#pragma unroll
  for (int s = 0; s < 4; s++) {
    int row = wave * 4 + s;
    float v1 = xs[row * 132 + lane];
    float v2 = xs[row * 132 + lane + 64];
    float s1 = v1 + v2, s2 = v1 * v1 + v2 * v2;
#pragma unroll
    for (int off = 32; off >= 1; off >>= 1) {
      s1 += __shfl_xor(s1, off);
      s2 += __shfl_xor(s2, off);
    }
    float mu = s1 * (1.f / 128.f);
    float var = s2 * (1.f / 128.f) - mu * mu;
    float rstd = rsqrtf(var + 1e-5f);
    out[(size_t)(n0 + row) * Cn + lane]      = (v1 - mu) * rstd * lg1 + lb1v;
    out[(size_t)(n0 + row) * Cn + lane + 64] = (v2 - mu) * rstd * lg2 + lb2v;
  }
}

extern "C" void kernel_launch(void* const* d_in, const int* in_sizes, int n_in,
                              void* d_out, int out_size, void* d_ws, size_t ws_size,
                              hipStream_t stream) {
  const float* node_h     = (const float*)d_in[0];
  const float* edge_h     = (const float*)d_in[1];
  const int*   edge_index = (const int*)  d_in[2];
  const float* W1 = (const float*)d_in[3];
  const float* b1 = (const float*)d_in[4];
  const float* W2 = (const float*)d_in[5];
  const float* b2 = (const float*)d_in[6];
  const float* W3 = (const float*)d_in[7];
  const float* b3 = (const float*)d_in[8];
  const float* Wu = (const float*)d_in[9];
  const float* bu = (const float*)d_in[10];
  const float* ln_g = (const float*)d_in[11];
  const float* ln_b = (const float*)d_in[12];
  float* out   = (float*)d_out;
  short* wpack = (short*)d_ws;   // 192 KiB

  pack_weights<<<48, 256, 0, stream>>>(W1, W2, W3, Wu, wpack);
  node_update_kernel<<<(Bn * Nn) / 2, 512, 0, stream>>>(
      node_h, edge_h, edge_index, wpack, b1, b2, out);
  tail_kernel<<<(Bn * Nn) / G2, 256, 0, stream>>>(
      node_h, wpack, b3, bu, ln_g, ln_b, out);
}